// Round 1
// baseline (642.868 us; speedup 1.0000x reference)
//
#include <hip/hip_runtime.h>
#include <cstdint>
#include <cstddef>

#define B_SZ 65536
#define K_SZ 512

typedef __attribute__((ext_vector_type(8))) short bf16x8;
typedef __attribute__((ext_vector_type(8))) unsigned short u16x8;
typedef __attribute__((ext_vector_type(4))) float f32x4;

__device__ __forceinline__ unsigned short f2bf(float f) {
  union { float f; uint32_t u; } v; v.f = f;
  uint32_t u = v.u;
  uint32_t r = (u + 0x7FFFu + ((u >> 16) & 1u)) >> 16;  // RNE
  return (unsigned short)r;
}

// Pack combined A = [x_t | h_prev] as bf16 [B, 512]
__global__ __launch_bounds__(256) void pack_a_kernel(const float* __restrict__ x,
                                                     const float* __restrict__ hp,
                                                     unsigned short* __restrict__ out) {
  int i = blockIdx.x * 256 + threadIdx.x;  // chunk id in [0, B*64); 8 elems/chunk
  int row = i >> 6, c = i & 63;
  const float* src = (c < 32) ? (x + ((size_t)row << 8) + ((size_t)c << 3))
                              : (hp + ((size_t)row << 8) + ((size_t)(c - 32) << 3));
  float4 v0 = ((const float4*)src)[0];
  float4 v1 = ((const float4*)src)[1];
  u16x8 o;
  o[0] = f2bf(v0.x); o[1] = f2bf(v0.y); o[2] = f2bf(v0.z); o[3] = f2bf(v0.w);
  o[4] = f2bf(v1.x); o[5] = f2bf(v1.y); o[6] = f2bf(v1.z); o[7] = f2bf(v1.w);
  *((u16x8*)(out + ((size_t)i << 3))) = o;
}

// Pack W as bf16 [1024, 512], rows permuted to gate-interleaved tile order:
// rho = bn*128 + hhblk*64 + gate*16 + hh  <->  W_gate row (bn*32 + hhblk*16 + hh)
__global__ __launch_bounds__(256) void pack_w_kernel(const float* __restrict__ Wf,
                                                     const float* __restrict__ Wi,
                                                     const float* __restrict__ Wo,
                                                     const float* __restrict__ Wg,
                                                     unsigned short* __restrict__ out) {
  int i = blockIdx.x * 256 + threadIdx.x;  // chunk in [0, 1024*64)
  int rho = i >> 6, c = i & 63;
  int bn = rho >> 7, r = rho & 127;
  int hhblk = (r >> 6) & 1, gate = (r >> 4) & 3, hh = r & 15;
  int srow = bn * 32 + hhblk * 16 + hh;
  const float* W = (gate == 0) ? Wf : (gate == 1) ? Wi : (gate == 2) ? Wo : Wg;
  const float* src = W + (size_t)srow * 512 + ((size_t)c << 3);
  float4 v0 = ((const float4*)src)[0];
  float4 v1 = ((const float4*)src)[1];
  u16x8 o;
  o[0] = f2bf(v0.x); o[1] = f2bf(v0.y); o[2] = f2bf(v0.z); o[3] = f2bf(v0.w);
  o[4] = f2bf(v1.x); o[5] = f2bf(v1.y); o[6] = f2bf(v1.z); o[7] = f2bf(v1.w);
  *((u16x8*)(out + ((size_t)i << 3))) = o;
}

__device__ __forceinline__ float sigmoid_f(float x) {
  return __builtin_amdgcn_rcpf(1.f + __expf(-x));
}
__device__ __forceinline__ float tanh_f(float x) {
  return 1.f - 2.f * __builtin_amdgcn_rcpf(__expf(2.f * x) + 1.f);
}

// GEMM: gates[m, n] = sum_k A[m,k] * Wb[n,k], tile BM=128 x BN=128(grouped) x BK=64.
// Grid: (8 n-tiles, 512 m-tiles), 256 threads = 4 waves, each wave 64x64 via 4x4
// mfma_f32_16x16x32_bf16 frags. n grouping puts all 4 gates of an h in one wave's
// 4 n-frags -> per-lane LSTM epilogue.
__global__ __launch_bounds__(256, 2) void lstm_gemm_kernel(
    const unsigned short* __restrict__ A, const unsigned short* __restrict__ Wb,
    const float* __restrict__ c_prev,
    const float* __restrict__ bf_, const float* __restrict__ bi_,
    const float* __restrict__ bo_, const float* __restrict__ bg_,
    float* __restrict__ out) {
  __shared__ __align__(16) unsigned short As[128 * 64];
  __shared__ __align__(16) unsigned short Bs[128 * 64];
  const int bn = blockIdx.x;       // 0..7 : h-block of 32
  const int m0 = blockIdx.y << 7;  // m-tile * 128
  const int t = threadIdx.x;
  const int lane = t & 63, w = t >> 6;
  const int r15 = lane & 15, quad = lane >> 4;

  f32x4 zero = {0.f, 0.f, 0.f, 0.f};
  f32x4 acc[4][4];
#pragma unroll
  for (int a = 0; a < 4; ++a)
#pragma unroll
    for (int b = 0; b < 4; ++b) acc[a][b] = zero;

  const int mbase = (w & 1) << 6;   // m offset within tile: 0 or 64
  const int nbase = (w >> 1) << 6;  // n_local offset: 0 or 64 (hhblk)

  for (int kt = 0; kt < 8; ++kt) {
    const int k0 = kt << 6;
    if (kt) __syncthreads();
    // global -> LDS, 16B/lane, XOR-swizzled chunk within each 128B row so the
    // ds_read_b128 fragment reads are ~conflict-free while staying contiguous.
#pragma unroll
    for (int j = 0; j < 4; ++j) {
      int l = (j << 8) + t;          // linear 16B-chunk id in tile [0,1024)
      int row = l >> 3, st = l & 7;  // LDS chunk slot
      int c = st ^ (row & 7);        // global chunk fetched into that slot
      const unsigned short* ga = A + (size_t)(m0 + row) * 512 + k0 + (c << 3);
      __builtin_amdgcn_global_load_lds(
          (const __attribute__((address_space(1))) void*)ga,
          (__attribute__((address_space(3))) void*)(As + ((size_t)l << 3)), 16, 0, 0);
      const unsigned short* gb = Wb + (size_t)((bn << 7) + row) * 512 + k0 + (c << 3);
      __builtin_amdgcn_global_load_lds(
          (const __attribute__((address_space(1))) void*)gb,
          (__attribute__((address_space(3))) void*)(Bs + ((size_t)l << 3)), 16, 0, 0);
    }
    __syncthreads();
#pragma unroll
    for (int ks = 0; ks < 2; ++ks) {
      bf16x8 af[4], bfr[4];
      const int ch = (ks << 2) + quad;
#pragma unroll
      for (int mi = 0; mi < 4; ++mi) {
        int row = mbase + (mi << 4) + r15;
        af[mi] = *((const bf16x8*)(As + (row << 6) + ((ch ^ (row & 7)) << 3)));
      }
#pragma unroll
      for (int gi = 0; gi < 4; ++gi) {
        int row = nbase + (gi << 4) + r15;
        bfr[gi] = *((const bf16x8*)(Bs + (row << 6) + ((ch ^ (row & 7)) << 3)));
      }
#pragma unroll
      for (int mi = 0; mi < 4; ++mi)
#pragma unroll
        for (int gi = 0; gi < 4; ++gi)
          acc[mi][gi] = __builtin_amdgcn_mfma_f32_16x16x32_bf16(af[mi], bfr[gi],
                                                                acc[mi][gi], 0, 0, 0);
    }
  }

  // Fused LSTM epilogue: lane holds f,i,o,g pre-activations for its (m,h) cells.
  const int h = (bn << 5) + ((w >> 1) << 4) + r15;  // global h in [0,256)
  const float Bf = bf_[h], Bi = bi_[h], Bo = bo_[h], Bg = bg_[h];
  const size_t S = (size_t)B_SZ * 256;
#pragma unroll
  for (int mi = 0; mi < 4; ++mi) {
    const int mr0 = m0 + mbase + (mi << 4) + (quad << 2);
#pragma unroll
    for (int r = 0; r < 4; ++r) {
      const int m = mr0 + r;
      float F = acc[mi][0][r] + Bf;
      float I = acc[mi][1][r] + Bi;
      float O = acc[mi][2][r] + Bo;
      float G = acc[mi][3][r] + Bg;
      float f = sigmoid_f(F);
      float ii = sigmoid_f(I);
      float o = sigmoid_f(O);
      float g = tanh_f(G);
      size_t base = (size_t)m * 256 + h;
      float cp = c_prev[base];
      float ct = f * cp + ii * g;
      float ht = o * tanh_f(ct);
      out[base] = ht;
      out[S + base] = ct;
      out[2 * S + base] = f;
      out[3 * S + base] = ii;
      out[4 * S + base] = o;
      out[5 * S + base] = g;
    }
  }
}

extern "C" void kernel_launch(void* const* d_in, const int* in_sizes, int n_in,
                              void* d_out, int out_size, void* d_ws, size_t ws_size,
                              hipStream_t stream) {
  const float* x   = (const float*)d_in[0];
  const float* hp  = (const float*)d_in[1];
  const float* cp  = (const float*)d_in[2];
  const float* Wf  = (const float*)d_in[3];
  const float* bf_ = (const float*)d_in[4];
  const float* Wi  = (const float*)d_in[5];
  const float* bi_ = (const float*)d_in[6];
  const float* Wo  = (const float*)d_in[7];
  const float* bo_ = (const float*)d_in[8];
  const float* Wg  = (const float*)d_in[9];
  const float* bg_ = (const float*)d_in[10];
  float* out = (float*)d_out;

  unsigned short* Apack = (unsigned short*)d_ws;                       // 64 MiB
  unsigned short* Wb = (unsigned short*)((char*)d_ws + (size_t)B_SZ * 512 * 2);  // 1 MiB

  pack_a_kernel<<<dim3((B_SZ * 64) / 256), dim3(256), 0, stream>>>(x, hp, Apack);
  pack_w_kernel<<<dim3((1024 * 64) / 256), dim3(256), 0, stream>>>(Wf, Wi, Wo, Wg, Wb);
  lstm_gemm_kernel<<<dim3(8, 512), dim3(256), 0, stream>>>(Apack, Wb, cp, bf_, bi_,
                                                           bo_, bg_, out);
}